// Round 1
// 768.954 us; speedup vs baseline: 1.8275x; 1.8275x over previous
//
#include <hip/hip_runtime.h>

// SimpleConcatAttention on MI355X — MFMA round (split-bf16 emulation of f32).
// Phases: 1) qW=(q@W)/32 split-bf16 MFMA  2) S=qW@key^T split-bf16 MFMA
//         3) masked softmax f32 (unchanged)  4) out=att@key plain-bf16 MFMA.
// Split math: x = hi(bf16) + lo(bf16); C ≈ Ah·Bh + Ah·Bl + Al·Bh (f32 MFMA acc).
// Dropped lo·lo ~2^-18 rel/term -> score err ~5e-6 (K=1024). Phase-4 pure bf16:
// out err ~1e-4. Both well under the previously measured f32-path absmax 9.8e-4.
// MFMA 16x16x32_bf16; C/D layout (HW-verified): col=lane&15, row=(lane>>4)*4+reg.
// A/B frag: row/col = lane&15, k = 4*(lane>>4)+{0..3} per 16-k half (permutation-
// safe: A and B share the (lane,elem)->k map, so any mis-guess cancels in the dot).

typedef float f32x4 __attribute__((ext_vector_type(4)));
typedef short bf16x8 __attribute__((ext_vector_type(8)));
typedef short s16x4 __attribute__((ext_vector_type(4)));

// f32 -> bf16 (RNE), and exact re-expansion for the lo residual.
__device__ __forceinline__ unsigned short f2bf(float f) {
    unsigned int u = __float_as_uint(f);
    return (unsigned short)((u + 0x7fffu + ((u >> 16) & 1u)) >> 16);
}
__device__ __forceinline__ float bf2f(unsigned short h) {
    return __uint_as_float(((unsigned int)h) << 16);
}

// LDS tile: [128 rows][32 k] bf16, row stride 36 (8B-aligned), k-offset XOR
// swizzle keyed on row bits to spread the 72B row stride across banks for both
// the ds_read_b64 frag loads and the transpose-staging b32 writes.
#define LDS_STRIDE 36
__device__ __forceinline__ int swz(int row, int k) {
    return row * LDS_STRIDE + (k ^ (((row >> 2) & 7) << 2));
}

// Load one 16x16x32 A/B fragment for this lane from an LDS plane.
// row = (tile base + lane&15), kg = 4*(lane>>4). Halves fetched with explicit
// swizzle (XOR may carry bit4, so the +16 half is NOT ptr+16 in general).
__device__ __forceinline__ bf16x8 ld_frag(const unsigned short* plane, int row, int kg) {
    s16x4 a = *(const s16x4*)(plane + swz(row, kg));
    s16x4 b = *(const s16x4*)(plane + swz(row, kg + 16));
    bf16x8 r = {a[0], a[1], a[2], a[3], b[0], b[1], b[2], b[3]};
    return r;
}

// ---------------------------------------------------------------------------
// MFMA GEMM: C[z] = scale * A[z] (.) B[z].  Tile 128x128, BK=32, 256 thr/4 waves,
// each wave owns a 64x64 sub-tile as 4x4 fragments of 16x16.
// BT=true : B stored [N x K] row-major -> C = A @ B^T (natural k-contiguous stage)
// BT=false: B stored [K x N] row-major -> C = A @ B   (transpose-staged into [n][k])
// SPLIT   : hi/lo bf16 planes + 3-MFMA emulation; else hi-plane only, 1 MFMA.
// ---------------------------------------------------------------------------
template<bool BT, bool SPLIT>
__global__ __launch_bounds__(256, 2) void gemm_mfma(
    const float* __restrict__ A, const float* __restrict__ B,
    float* __restrict__ C,
    int Kd, int lda, int ldb, int ldc,
    long sA, long sB, long sC, float scale)
{
    constexpr int PLANES = SPLIT ? 2 : 1;
    __shared__ unsigned short As[PLANES][128 * LDS_STRIDE];
    __shared__ unsigned short Bs[PLANES][128 * LDS_STRIDE];

    const int tid  = threadIdx.x;
    const int lane = tid & 63;
    const int wave = tid >> 6;
    const int wm = (wave >> 1) * 64;       // wave's 64x64 sub-tile origin
    const int wn = (wave & 1) * 64;
    const int lr = lane & 15;              // row (A) / col (B) within 16-tile
    const int kg = (lane >> 4) * 4;        // per-lane k group

    const int m0 = blockIdx.y * 128, n0 = blockIdx.x * 128;
    const float* Ag = A + (long)blockIdx.z * sA + (long)m0 * lda;
    const float* Bg = B + (long)blockIdx.z * sB + (BT ? (long)n0 * ldb : (long)n0);

    f32x4 acc[4][4] = {};

    for (int k0 = 0; k0 < Kd; k0 += 32) {
        __syncthreads();

        // ---- stage A [128 m x 32 k] f32 -> bf16 hi(/lo) planes ----
#pragma unroll
        for (int it = 0; it < 4; it++) {
            const int idx = tid + it * 256;
            const int row = idx >> 3, kc = (idx & 7) * 4;
            f32x4 v = *(const f32x4*)(Ag + (long)row * lda + k0 + kc);
            ushort4 h;
            h.x = f2bf(v[0]); h.y = f2bf(v[1]); h.z = f2bf(v[2]); h.w = f2bf(v[3]);
            *(ushort4*)&As[0][swz(row, kc)] = h;
            if constexpr (SPLIT) {
                ushort4 l;
                l.x = f2bf(v[0] - bf2f(h.x)); l.y = f2bf(v[1] - bf2f(h.y));
                l.z = f2bf(v[2] - bf2f(h.z)); l.w = f2bf(v[3] - bf2f(h.w));
                *(ushort4*)&As[1][swz(row, kc)] = l;
            }
        }

        // ---- stage B ----
        if constexpr (BT) {                // [128 n x 32 k]: same pattern as A
#pragma unroll
            for (int it = 0; it < 4; it++) {
                const int idx = tid + it * 256;
                const int row = idx >> 3, kc = (idx & 7) * 4;
                f32x4 v = *(const f32x4*)(Bg + (long)row * ldb + k0 + kc);
                ushort4 h;
                h.x = f2bf(v[0]); h.y = f2bf(v[1]); h.z = f2bf(v[2]); h.w = f2bf(v[3]);
                *(ushort4*)&Bs[0][swz(row, kc)] = h;
                if constexpr (SPLIT) {
                    ushort4 l;
                    l.x = f2bf(v[0] - bf2f(h.x)); l.y = f2bf(v[1] - bf2f(h.y));
                    l.z = f2bf(v[2] - bf2f(h.z)); l.w = f2bf(v[3] - bf2f(h.w));
                    *(ushort4*)&Bs[1][swz(row, kc)] = l;
                }
            }
        } else {                           // [32 k x 128 n]: transpose-stage to [n][k]
                                           // k-pairs packed as u32 to halve write count
#pragma unroll
            for (int it = 0; it < 2; it++) {
                const int idx = tid + it * 256;          // 512 chunks of (2k x 4n)
                const int kk = (idx >> 5) * 2;
                const int nc = (idx & 31) * 4;
                f32x4 v0 = *(const f32x4*)(Bg + (long)(k0 + kk) * ldb + nc);
                f32x4 v1 = *(const f32x4*)(Bg + (long)(k0 + kk + 1) * ldb + nc);
#pragma unroll
                for (int e = 0; e < 4; e++) {
                    const unsigned short h0 = f2bf(v0[e]), h1 = f2bf(v1[e]);
                    *(unsigned int*)&Bs[0][swz(nc + e, kk)] =
                        (unsigned int)h0 | ((unsigned int)h1 << 16);
                    if constexpr (SPLIT) {
                        const unsigned short l0 = f2bf(v0[e] - bf2f(h0));
                        const unsigned short l1 = f2bf(v1[e] - bf2f(h1));
                        *(unsigned int*)&Bs[1][swz(nc + e, kk)] =
                            (unsigned int)l0 | ((unsigned int)l1 << 16);
                    }
                }
            }
        }
        __syncthreads();

        // ---- fragment loads + MFMA ----
        bf16x8 ah[4], bh[4], al[4], bl[4];
#pragma unroll
        for (int i = 0; i < 4; i++) {
            ah[i] = ld_frag(&As[0][0], wm + i * 16 + lr, kg);
            if constexpr (SPLIT) al[i] = ld_frag(&As[1][0], wm + i * 16 + lr, kg);
        }
#pragma unroll
        for (int j = 0; j < 4; j++) {
            bh[j] = ld_frag(&Bs[0][0], wn + j * 16 + lr, kg);
            if constexpr (SPLIT) bl[j] = ld_frag(&Bs[1][0], wn + j * 16 + lr, kg);
        }
#pragma unroll
        for (int i = 0; i < 4; i++)
#pragma unroll
            for (int j = 0; j < 4; j++) {
                acc[i][j] = __builtin_amdgcn_mfma_f32_16x16x32_bf16(
                    ah[i], bh[j], acc[i][j], 0, 0, 0);
                if constexpr (SPLIT) {
                    acc[i][j] = __builtin_amdgcn_mfma_f32_16x16x32_bf16(
                        ah[i], bl[j], acc[i][j], 0, 0, 0);
                    acc[i][j] = __builtin_amdgcn_mfma_f32_16x16x32_bf16(
                        al[i], bh[j], acc[i][j], 0, 0, 0);
                }
            }
    }

    // ---- epilogue: C/D layout col=lane&15, row=(lane>>4)*4+reg ----
    float* Cg = C + (long)blockIdx.z * sC + (long)(m0 + wm) * ldc + n0 + wn;
    const int rbase = (lane >> 4) * 4;
#pragma unroll
    for (int i = 0; i < 4; i++)
#pragma unroll
        for (int r = 0; r < 4; r++) {
            float* cp = Cg + (long)(i * 16 + rbase + r) * ldc + lr;
#pragma unroll
            for (int j = 0; j < 4; j++)
                cp[j * 16] = acc[i][j][r] * scale;
        }
}

// ---------------------------------------------------------------------------
// Masked softmax over rows of 2048, in place on f32 scores. mask int32 (!=0).
// One block (256 thr) per row; each thread owns 8 contiguous elements.
// ---------------------------------------------------------------------------
__global__ __launch_bounds__(256) void softmax_rows(
    float* __restrict__ att, const int* __restrict__ mask)
{
    const int  row  = blockIdx.x;                    // b*512 + k
    const int  tid  = threadIdx.x;
    const long base = (long)row * 2048 + tid * 8;

    f32x4 s0 = *(const f32x4*)(att + base);
    f32x4 s1 = *(const f32x4*)(att + base + 4);
    int4  mv0 = *(const int4*)(mask + base);
    int4  mv1 = *(const int4*)(mask + base + 4);
    const int mk[8] = {mv0.x, mv0.y, mv0.z, mv0.w, mv1.x, mv1.y, mv1.z, mv1.w};

    float x[8] = {s0[0], s0[1], s0[2], s0[3], s1[0], s1[1], s1[2], s1[3]};
#pragma unroll
    for (int j = 0; j < 8; j++) x[j] = mk[j] ? x[j] : -INFINITY;

    float mx = x[0];
#pragma unroll
    for (int j = 1; j < 8; j++) mx = fmaxf(mx, x[j]);
#pragma unroll
    for (int off = 32; off > 0; off >>= 1) mx = fmaxf(mx, __shfl_down(mx, off));

    __shared__ float red[8];
    const int wave = tid >> 6, lane = tid & 63;
    if (lane == 0) red[wave] = mx;
    __syncthreads();
    mx = fmaxf(fmaxf(red[0], red[1]), fmaxf(red[2], red[3]));

    if (mx == -INFINITY) {                           // all-masked row: zeros, not NaN
        f32x4 z = {0.f, 0.f, 0.f, 0.f};
        *(f32x4*)(att + base) = z;
        *(f32x4*)(att + base + 4) = z;
        return;
    }

    float e[8], s = 0.f;
#pragma unroll
    for (int j = 0; j < 8; j++) { e[j] = __expf(x[j] - mx); s += e[j]; }
#pragma unroll
    for (int off = 32; off > 0; off >>= 1) s += __shfl_down(s, off);
    if (lane == 0) red[4 + wave] = s;
    __syncthreads();
    s = red[4] + red[5] + red[6] + red[7];

    const float inv = 1.f / s;
    f32x4 o0, o1;
#pragma unroll
    for (int j = 0; j < 4; j++) { o0[j] = e[j] * inv; o1[j] = e[4 + j] * inv; }
    *(f32x4*)(att + base) = o0;
    *(f32x4*)(att + base + 4) = o1;
}

// ---------------------------------------------------------------------------
extern "C" void kernel_launch(void* const* d_in, const int* in_sizes, int n_in,
                              void* d_out, int out_size, void* d_ws, size_t ws_size,
                              hipStream_t stream)
{
    // Identify inputs by unique element count (robust to ordering).
    const float* query = nullptr;   // 512*1024      = 524288
    const float* key   = nullptr;   // 16*2048*1024  = 33554432
    const float* W     = nullptr;   // 1024*1024     = 1048576
    const int*   mask  = nullptr;   // 16*512*2048   = 16777216
    for (int i = 0; i < n_in; i++) {
        switch (in_sizes[i]) {
            case 524288:   query = (const float*)d_in[i]; break;
            case 33554432: key   = (const float*)d_in[i]; break;
            case 1048576:  W     = (const float*)d_in[i]; break;
            case 16777216: mask  = (const int*)d_in[i];   break;
        }
    }

    float* out = (float*)d_out;                     // [16,512,1024] f32
    float* att = out + (long)16 * 512 * 1024;       // [16,512,2048] f32
    float* qW  = out;                               // f32 scratch (dead before phase 4 writes)

    // 1) qW = (query @ W) / 32      [512 x 1024], K=1024.  NN, split-bf16.
    gemm_mfma<false, true><<<dim3(8, 4, 1), 256, 0, stream>>>(
        query, W, qW, 1024, 1024, 1024, 1024,
        0L, 0L, 0L, 1.f / 32.f);

    // 2) S[b] = qW @ key[b]^T       [512 x 2048], K=1024.  NT, split-bf16.
    gemm_mfma<true, true><<<dim3(16, 4, 16), 256, 0, stream>>>(
        qW, key, att, 1024, 1024, 1024, 2048,
        0L, (long)2048 * 1024, (long)512 * 2048, 1.f);

    // 3) masked softmax in place (f32 throughout)
    softmax_rows<<<dim3(16 * 512), 256, 0, stream>>>(att, mask);

    // 4) out[b] = att[b] @ key[b]   [512 x 1024], K=2048.  NN, plain bf16
    //    (att produced in f32 by softmax; bf16 rounding of p contributes ~1e-4).
    gemm_mfma<false, false><<<dim3(8, 4, 16), 256, 0, stream>>>(
        att, key, out, 2048, 2048, 1024, 1024,
        (long)512 * 2048, (long)2048 * 1024, (long)512 * 1024, 1.f);
}

// Round 2
// 725.353 us; speedup vs baseline: 1.9374x; 1.0601x over previous
//
#include <hip/hip_runtime.h>

// SimpleConcatAttention on MI355X — MFMA round 2 (cvt_pk staging).
// Phases: 1) qW=(q@W)/32 split-bf16 MFMA  2) S=qW@key^T split-bf16 MFMA
//         3) masked softmax f32 (unchanged)  4) out=att@key plain-bf16 MFMA.
// Split math: x = hi(bf16) + lo(bf16); C ≈ Ah·Bh + Ah·Bl + Al·Bh (f32 MFMA acc).
// Round-2 changes vs round 1 (which measured 769 µs, MfmaUtil 20%, VALUBusy 34%):
//  * f32->bf16 via v_cvt_pk_bf16_f32 (1 instr / 2 elems) instead of 4-instr
//    bit-twiddle: staging VALU ~3x down. (v_cvt_pk_bf16_f32 packs src0 into
//    D[15:0], src1 into D[31:16] — same convention as v_cvt_pkrtz_f16_f32;
//    both A and B planes pack k-pairs through the same helper, so even a
//    hi/lo-half swap would cancel in the dot product for the hi plane.)
//  * swizzle gains a row-bit5 term: fixes the 4-way alias of the BT=false
//    transpose-staging u32 writes (rows 8 apart hit the same bank).
//  * __launch_bounds__(256,3): guarantee 3 blocks/CU under the unified
//    VGPR+AGPR file (~156 regs/wave: 64 acc AGPR + ~92 VGPR).

typedef float f32x4 __attribute__((ext_vector_type(4)));
typedef short bf16x8 __attribute__((ext_vector_type(8)));
typedef short s16x4 __attribute__((ext_vector_type(4)));

// Pack 2 f32 -> 2 bf16 (RNE, hardware). D[15:0]=cvt(a), D[31:16]=cvt(b).
__device__ __forceinline__ unsigned cvt2(float a, float b) {
    unsigned r;
    asm("v_cvt_pk_bf16_f32 %0, %1, %2" : "=v"(r) : "v"(a), "v"(b));
    return r;
}
// Re-expand the two bf16 halves of a packed u32 to f32 (exact).
__device__ __forceinline__ float lo_f(unsigned p) { return __uint_as_float(p << 16); }
__device__ __forceinline__ float hi_f(unsigned p) { return __uint_as_float(p & 0xffff0000u); }

// LDS tile: [128 rows][32 k] bf16, row stride 36 u16 (72 B; rows cycle all 16
// even bank-phases). XOR swizzle: granule-4 key ((row>>2)&7) spreads frag reads
// uniformly; added ((row>>5)&1)<<4 term de-aliases stride-4-row staging writes
// (rows 8 apart previously mapped to the same bank: 18*8 ≡ 0 mod 32 and the
// 3-bit key dropped row bit 5). Both terms are constant within any 16-row
// fragment group, so frag-read uniformity is preserved.
#define LDS_STRIDE 36
__device__ __forceinline__ int swz(int row, int k) {
    return row * LDS_STRIDE + (k ^ (((row >> 2) & 7) << 2) ^ (((row >> 5) & 1) << 4));
}

// Load one 16x16x32 A/B fragment for this lane from an LDS plane.
// XOR can carry bit4, so the +16 half is a separate swizzled address.
__device__ __forceinline__ bf16x8 ld_frag(const unsigned short* plane, int row, int kg) {
    s16x4 a = *(const s16x4*)(plane + swz(row, kg));
    s16x4 b = *(const s16x4*)(plane + swz(row, kg + 16));
    bf16x8 r = {a[0], a[1], a[2], a[3], b[0], b[1], b[2], b[3]};
    return r;
}

// ---------------------------------------------------------------------------
// MFMA GEMM: C[z] = scale * A[z] (.) B[z].  Tile 128x128, BK=32, 256 thr/4 waves,
// each wave owns a 64x64 sub-tile as 4x4 fragments of 16x16.
// BT=true : B stored [N x K] row-major -> C = A @ B^T (k-contiguous staging)
// BT=false: B stored [K x N] row-major -> C = A @ B   (transpose-staged to [n][k])
// SPLIT   : hi/lo bf16 planes + 3-MFMA emulation; else hi plane only, 1 MFMA.
// ---------------------------------------------------------------------------
template<bool BT, bool SPLIT>
__global__ __launch_bounds__(256, 3) void gemm_mfma(
    const float* __restrict__ A, const float* __restrict__ B,
    float* __restrict__ C,
    int Kd, int lda, int ldb, int ldc,
    long sA, long sB, long sC, float scale)
{
    constexpr int PLANES = SPLIT ? 2 : 1;
    __shared__ unsigned short As[PLANES][128 * LDS_STRIDE];
    __shared__ unsigned short Bs[PLANES][128 * LDS_STRIDE];

    const int tid  = threadIdx.x;
    const int lane = tid & 63;
    const int wave = tid >> 6;
    const int wm = (wave >> 1) * 64;       // wave's 64x64 sub-tile origin
    const int wn = (wave & 1) * 64;
    const int lr = lane & 15;              // row (A) / col (B) within 16-tile
    const int kg = (lane >> 4) * 4;        // per-lane k group

    const int m0 = blockIdx.y * 128, n0 = blockIdx.x * 128;
    const float* Ag = A + (long)blockIdx.z * sA + (long)m0 * lda;
    const float* Bg = B + (long)blockIdx.z * sB + (BT ? (long)n0 * ldb : (long)n0);

    f32x4 acc[4][4] = {};

    for (int k0 = 0; k0 < Kd; k0 += 32) {
        __syncthreads();

        // ---- stage A [128 m x 32 k] f32 -> bf16 hi(/lo) planes ----
#pragma unroll
        for (int it = 0; it < 4; it++) {
            const int idx = tid + it * 256;
            const int row = idx >> 3, kc = (idx & 7) * 4;
            f32x4 v = *(const f32x4*)(Ag + (long)row * lda + k0 + kc);
            const unsigned h01 = cvt2(v[0], v[1]), h23 = cvt2(v[2], v[3]);
            uint2 hw = {h01, h23};
            *(uint2*)&As[0][swz(row, kc)] = hw;          // offset %4==0 -> 8B aligned
            if constexpr (SPLIT) {
                uint2 lw = {cvt2(v[0] - lo_f(h01), v[1] - hi_f(h01)),
                            cvt2(v[2] - lo_f(h23), v[3] - hi_f(h23))};
                *(uint2*)&As[1][swz(row, kc)] = lw;
            }
        }

        // ---- stage B ----
        if constexpr (BT) {                // [128 n x 32 k]: same pattern as A
#pragma unroll
            for (int it = 0; it < 4; it++) {
                const int idx = tid + it * 256;
                const int row = idx >> 3, kc = (idx & 7) * 4;
                f32x4 v = *(const f32x4*)(Bg + (long)row * ldb + k0 + kc);
                const unsigned h01 = cvt2(v[0], v[1]), h23 = cvt2(v[2], v[3]);
                uint2 hw = {h01, h23};
                *(uint2*)&Bs[0][swz(row, kc)] = hw;
                if constexpr (SPLIT) {
                    uint2 lw = {cvt2(v[0] - lo_f(h01), v[1] - hi_f(h01)),
                                cvt2(v[2] - lo_f(h23), v[3] - hi_f(h23))};
                    *(uint2*)&Bs[1][swz(row, kc)] = lw;
                }
            }
        } else {                           // [32 k x 128 n]: transpose-stage to [n][k]
                                           // k-pairs packed by cvt2 (same pair order
                                           // as the A-plane packing).
#pragma unroll
            for (int it = 0; it < 2; it++) {
                const int idx = tid + it * 256;          // 512 chunks of (2k x 4n)
                const int kk = (idx >> 5) * 2;
                const int nc = (idx & 31) * 4;
                f32x4 v0 = *(const f32x4*)(Bg + (long)(k0 + kk) * ldb + nc);
                f32x4 v1 = *(const f32x4*)(Bg + (long)(k0 + kk + 1) * ldb + nc);
#pragma unroll
                for (int e = 0; e < 4; e++) {
                    const unsigned p = cvt2(v0[e], v1[e]);
                    *(unsigned*)&Bs[0][swz(nc + e, kk)] = p;
                    if constexpr (SPLIT) {
                        *(unsigned*)&Bs[1][swz(nc + e, kk)] =
                            cvt2(v0[e] - lo_f(p), v1[e] - hi_f(p));
                    }
                }
            }
        }
        __syncthreads();

        // ---- fragment loads + MFMA ----
        bf16x8 ah[4], bh[4], al[4], bl[4];
#pragma unroll
        for (int i = 0; i < 4; i++) {
            ah[i] = ld_frag(&As[0][0], wm + i * 16 + lr, kg);
            if constexpr (SPLIT) al[i] = ld_frag(&As[1][0], wm + i * 16 + lr, kg);
        }
#pragma unroll
        for (int j = 0; j < 4; j++) {
            bh[j] = ld_frag(&Bs[0][0], wn + j * 16 + lr, kg);
            if constexpr (SPLIT) bl[j] = ld_frag(&Bs[1][0], wn + j * 16 + lr, kg);
        }
#pragma unroll
        for (int i = 0; i < 4; i++)
#pragma unroll
            for (int j = 0; j < 4; j++) {
                acc[i][j] = __builtin_amdgcn_mfma_f32_16x16x32_bf16(
                    ah[i], bh[j], acc[i][j], 0, 0, 0);
                if constexpr (SPLIT) {
                    acc[i][j] = __builtin_amdgcn_mfma_f32_16x16x32_bf16(
                        ah[i], bl[j], acc[i][j], 0, 0, 0);
                    acc[i][j] = __builtin_amdgcn_mfma_f32_16x16x32_bf16(
                        al[i], bh[j], acc[i][j], 0, 0, 0);
                }
            }
    }

    // ---- epilogue: C/D layout col=lane&15, row=(lane>>4)*4+reg ----
    float* Cg = C + (long)blockIdx.z * sC + (long)(m0 + wm) * ldc + n0 + wn;
    const int rbase = (lane >> 4) * 4;
#pragma unroll
    for (int i = 0; i < 4; i++)
#pragma unroll
        for (int r = 0; r < 4; r++) {
            float* cp = Cg + (long)(i * 16 + rbase + r) * ldc + lr;
#pragma unroll
            for (int j = 0; j < 4; j++)
                cp[j * 16] = acc[i][j][r] * scale;
        }
}

// ---------------------------------------------------------------------------
// Masked softmax over rows of 2048, in place on f32 scores. mask int32 (!=0).
// One block (256 thr) per row; each thread owns 8 contiguous elements.
// ---------------------------------------------------------------------------
__global__ __launch_bounds__(256) void softmax_rows(
    float* __restrict__ att, const int* __restrict__ mask)
{
    const int  row  = blockIdx.x;                    // b*512 + k
    const int  tid  = threadIdx.x;
    const long base = (long)row * 2048 + tid * 8;

    f32x4 s0 = *(const f32x4*)(att + base);
    f32x4 s1 = *(const f32x4*)(att + base + 4);
    int4  mv0 = *(const int4*)(mask + base);
    int4  mv1 = *(const int4*)(mask + base + 4);
    const int mk[8] = {mv0.x, mv0.y, mv0.z, mv0.w, mv1.x, mv1.y, mv1.z, mv1.w};

    float x[8] = {s0[0], s0[1], s0[2], s0[3], s1[0], s1[1], s1[2], s1[3]};
#pragma unroll
    for (int j = 0; j < 8; j++) x[j] = mk[j] ? x[j] : -INFINITY;

    float mx = x[0];
#pragma unroll
    for (int j = 1; j < 8; j++) mx = fmaxf(mx, x[j]);
#pragma unroll
    for (int off = 32; off > 0; off >>= 1) mx = fmaxf(mx, __shfl_down(mx, off));

    __shared__ float red[8];
    const int wave = tid >> 6, lane = tid & 63;
    if (lane == 0) red[wave] = mx;
    __syncthreads();
    mx = fmaxf(fmaxf(red[0], red[1]), fmaxf(red[2], red[3]));

    if (mx == -INFINITY) {                           // all-masked row: zeros, not NaN
        f32x4 z = {0.f, 0.f, 0.f, 0.f};
        *(f32x4*)(att + base) = z;
        *(f32x4*)(att + base + 4) = z;
        return;
    }

    float e[8], s = 0.f;
#pragma unroll
    for (int j = 0; j < 8; j++) { e[j] = __expf(x[j] - mx); s += e[j]; }
#pragma unroll
    for (int off = 32; off > 0; off >>= 1) s += __shfl_down(s, off);
    if (lane == 0) red[4 + wave] = s;
    __syncthreads();
    s = red[4] + red[5] + red[6] + red[7];

    const float inv = 1.f / s;
    f32x4 o0, o1;
#pragma unroll
    for (int j = 0; j < 4; j++) { o0[j] = e[j] * inv; o1[j] = e[4 + j] * inv; }
    *(f32x4*)(att + base) = o0;
    *(f32x4*)(att + base + 4) = o1;
}

// ---------------------------------------------------------------------------
extern "C" void kernel_launch(void* const* d_in, const int* in_sizes, int n_in,
                              void* d_out, int out_size, void* d_ws, size_t ws_size,
                              hipStream_t stream)
{
    // Identify inputs by unique element count (robust to ordering).
    const float* query = nullptr;   // 512*1024      = 524288
    const float* key   = nullptr;   // 16*2048*1024  = 33554432
    const float* W     = nullptr;   // 1024*1024     = 1048576
    const int*   mask  = nullptr;   // 16*512*2048   = 16777216
    for (int i = 0; i < n_in; i++) {
        switch (in_sizes[i]) {
            case 524288:   query = (const float*)d_in[i]; break;
            case 33554432: key   = (const float*)d_in[i]; break;
            case 1048576:  W     = (const float*)d_in[i]; break;
            case 16777216: mask  = (const int*)d_in[i];   break;
        }
    }

    float* out = (float*)d_out;                     // [16,512,1024] f32
    float* att = out + (long)16 * 512 * 1024;       // [16,512,2048] f32
    float* qW  = out;                               // f32 scratch (dead before phase 4 writes)

    // 1) qW = (query @ W) / 32      [512 x 1024], K=1024.  NN, split-bf16.
    gemm_mfma<false, true><<<dim3(8, 4, 1), 256, 0, stream>>>(
        query, W, qW, 1024, 1024, 1024, 1024,
        0L, 0L, 0L, 1.f / 32.f);

    // 2) S[b] = qW @ key[b]^T       [512 x 2048], K=1024.  NT, split-bf16.
    gemm_mfma<true, true><<<dim3(16, 4, 16), 256, 0, stream>>>(
        qW, key, att, 1024, 1024, 1024, 2048,
        0L, (long)2048 * 1024, (long)512 * 2048, 1.f);

    // 3) masked softmax in place (f32 throughout)
    softmax_rows<<<dim3(16 * 512), 256, 0, stream>>>(att, mask);

    // 4) out[b] = att[b] @ key[b]   [512 x 1024], K=2048.  NN, plain bf16
    //    (att produced in f32 by softmax; bf16 rounding of p contributes ~1e-4).
    gemm_mfma<false, false><<<dim3(8, 4, 16), 256, 0, stream>>>(
        att, key, out, 2048, 2048, 1024, 1024,
        (long)512 * 2048, (long)2048 * 1024, (long)512 * 1024, 1.f);
}

// Round 3
// 650.755 us; speedup vs baseline: 2.1595x; 1.1146x over previous
//
#include <hip/hip_runtime.h>

// SimpleConcatAttention on MI355X — round 3: pre-converted bf16 operands.
// Round-2 post-mortem: inline-asm cvt_pk broke compiler scheduling (both MfmaUtil
// and VALUBusy collapsed; −58% on both GEMM phases — matches the documented m240
// "inline cvt_pk is −37% vs scalar cast" lesson). Round 3 removes conversion from
// the GEMM hot loops entirely:
//   0) split key f32 -> key_hi/key_lo bf16 planes in ws (one memory-bound pass)
//   1) qW = (q@W)/32 via round-1 fused-conversion GEMM (3% of FLOPs, known-good)
//   2) split qW -> qW_hi/qW_lo (tiny)
//   3) S = qW@key^T: bf16-copy-staged MFMA GEMM, split (hi*hi+hi*lo+lo*hi)
//   4) softmax f32, dual-writing att as f32 (output) + bf16 (ws)
//   5) out = att@key: bf16-copy-staged MFMA GEMM, plain hi-only
// Fallback: if ws_size < ~172 MB, run the round-1 all-fused path (no ws needed).

typedef float f32x4 __attribute__((ext_vector_type(4)));
typedef short bf16x8 __attribute__((ext_vector_type(8)));
typedef short s16x4 __attribute__((ext_vector_type(4)));
typedef unsigned short u16;
typedef unsigned short u16x8 __attribute__((ext_vector_type(8)));

// f32 -> bf16 (RNE) bit-twiddle (compiler-visible; round-1-proven), exact expand.
__device__ __forceinline__ u16 f2bf(float f) {
    unsigned int u = __float_as_uint(f);
    return (u16)((u + 0x7fffu + ((u >> 16) & 1u)) >> 16);
}
__device__ __forceinline__ float bf2f(u16 h) {
    return __uint_as_float(((unsigned int)h) << 16);
}

// Load 8 bf16 (two 8B halves) from LDS at two precomputed u16 offsets.
__device__ __forceinline__ bf16x8 ld2(const u16* p, int off1, int off2) {
    s16x4 a = *(const s16x4*)(p + off1);
    s16x4 b = *(const s16x4*)(p + off2);
    bf16x8 r = {a[0], a[1], a[2], a[3], b[0], b[1], b[2], b[3]};
    return r;
}

// ===========================================================================
// Round-1 fused-conversion GEMM (f32 in, f32 out, converts in staging).
// Used for phase 1 (small) and as the no-workspace fallback. Verbatim round-1
// logic: LDS stride 36 + granule-4 XOR swizzle, launch_bounds(256,2).
// ===========================================================================
#define CSTR 36
__device__ __forceinline__ int swzc(int row, int k) {
    return row * CSTR + (k ^ (((row >> 2) & 7) << 2));
}
__device__ __forceinline__ bf16x8 ld_fragc(const u16* plane, int row, int kg) {
    return ld2(plane, swzc(row, kg), swzc(row, kg + 16));
}

template<bool BT, bool SPLIT>
__global__ __launch_bounds__(256, 2) void gemm_f32conv(
    const float* __restrict__ A, const float* __restrict__ B,
    float* __restrict__ C,
    int Kd, int lda, int ldb, int ldc,
    long sA, long sB, long sC, float scale)
{
    constexpr int PLANES = SPLIT ? 2 : 1;
    __shared__ u16 As[PLANES][128 * CSTR];
    __shared__ u16 Bs[PLANES][128 * CSTR];

    const int tid  = threadIdx.x;
    const int lane = tid & 63;
    const int wave = tid >> 6;
    const int wm = (wave >> 1) * 64, wn = (wave & 1) * 64;
    const int lr = lane & 15, kg = (lane >> 4) * 4;

    const int m0 = blockIdx.y * 128, n0 = blockIdx.x * 128;
    const float* Ag = A + (long)blockIdx.z * sA + (long)m0 * lda;
    const float* Bg = B + (long)blockIdx.z * sB + (BT ? (long)n0 * ldb : (long)n0);

    f32x4 acc[4][4] = {};

    for (int k0 = 0; k0 < Kd; k0 += 32) {
        __syncthreads();
#pragma unroll
        for (int it = 0; it < 4; it++) {
            const int idx = tid + it * 256;
            const int row = idx >> 3, kc = (idx & 7) * 4;
            f32x4 v = *(const f32x4*)(Ag + (long)row * lda + k0 + kc);
            ushort4 h;
            h.x = f2bf(v[0]); h.y = f2bf(v[1]); h.z = f2bf(v[2]); h.w = f2bf(v[3]);
            *(ushort4*)&As[0][swzc(row, kc)] = h;
            if constexpr (SPLIT) {
                ushort4 l;
                l.x = f2bf(v[0] - bf2f(h.x)); l.y = f2bf(v[1] - bf2f(h.y));
                l.z = f2bf(v[2] - bf2f(h.z)); l.w = f2bf(v[3] - bf2f(h.w));
                *(ushort4*)&As[1][swzc(row, kc)] = l;
            }
        }
        if constexpr (BT) {
#pragma unroll
            for (int it = 0; it < 4; it++) {
                const int idx = tid + it * 256;
                const int row = idx >> 3, kc = (idx & 7) * 4;
                f32x4 v = *(const f32x4*)(Bg + (long)row * ldb + k0 + kc);
                ushort4 h;
                h.x = f2bf(v[0]); h.y = f2bf(v[1]); h.z = f2bf(v[2]); h.w = f2bf(v[3]);
                *(ushort4*)&Bs[0][swzc(row, kc)] = h;
                if constexpr (SPLIT) {
                    ushort4 l;
                    l.x = f2bf(v[0] - bf2f(h.x)); l.y = f2bf(v[1] - bf2f(h.y));
                    l.z = f2bf(v[2] - bf2f(h.z)); l.w = f2bf(v[3] - bf2f(h.w));
                    *(ushort4*)&Bs[1][swzc(row, kc)] = l;
                }
            }
        } else {
#pragma unroll
            for (int it = 0; it < 2; it++) {
                const int idx = tid + it * 256;
                const int kk = (idx >> 5) * 2;
                const int nc = (idx & 31) * 4;
                f32x4 v0 = *(const f32x4*)(Bg + (long)(k0 + kk) * ldb + nc);
                f32x4 v1 = *(const f32x4*)(Bg + (long)(k0 + kk + 1) * ldb + nc);
#pragma unroll
                for (int e = 0; e < 4; e++) {
                    const u16 h0 = f2bf(v0[e]), h1 = f2bf(v1[e]);
                    *(unsigned*)&Bs[0][swzc(nc + e, kk)] =
                        (unsigned)h0 | ((unsigned)h1 << 16);
                    if constexpr (SPLIT) {
                        const u16 l0 = f2bf(v0[e] - bf2f(h0));
                        const u16 l1 = f2bf(v1[e] - bf2f(h1));
                        *(unsigned*)&Bs[1][swzc(nc + e, kk)] =
                            (unsigned)l0 | ((unsigned)l1 << 16);
                    }
                }
            }
        }
        __syncthreads();

        bf16x8 ah[4], bh[4], al[4], bl[4];
#pragma unroll
        for (int i = 0; i < 4; i++) {
            ah[i] = ld_fragc(&As[0][0], wm + i * 16 + lr, kg);
            if constexpr (SPLIT) al[i] = ld_fragc(&As[1][0], wm + i * 16 + lr, kg);
        }
#pragma unroll
        for (int j = 0; j < 4; j++) {
            bh[j] = ld_fragc(&Bs[0][0], wn + j * 16 + lr, kg);
            if constexpr (SPLIT) bl[j] = ld_fragc(&Bs[1][0], wn + j * 16 + lr, kg);
        }
#pragma unroll
        for (int i = 0; i < 4; i++)
#pragma unroll
            for (int j = 0; j < 4; j++) {
                acc[i][j] = __builtin_amdgcn_mfma_f32_16x16x32_bf16(
                    ah[i], bh[j], acc[i][j], 0, 0, 0);
                if constexpr (SPLIT) {
                    acc[i][j] = __builtin_amdgcn_mfma_f32_16x16x32_bf16(
                        ah[i], bl[j], acc[i][j], 0, 0, 0);
                    acc[i][j] = __builtin_amdgcn_mfma_f32_16x16x32_bf16(
                        al[i], bh[j], acc[i][j], 0, 0, 0);
                }
            }
    }

    float* Cg = C + (long)blockIdx.z * sC + (long)(m0 + wm) * ldc + n0 + wn;
    const int rbase = (lane >> 4) * 4;
#pragma unroll
    for (int i = 0; i < 4; i++)
#pragma unroll
        for (int r = 0; r < 4; r++) {
            float* cp = Cg + (long)(i * 16 + rbase + r) * ldc + lr;
#pragma unroll
            for (int j = 0; j < 4; j++)
                cp[j * 16] = acc[i][j][r] * scale;
        }
}

// ===========================================================================
// Elementwise split: src f32 -> hi/lo bf16 planes. n4 = element count / 4.
// ===========================================================================
__global__ __launch_bounds__(256) void split_f32(
    const float* __restrict__ src, u16* __restrict__ hi, u16* __restrict__ lo,
    long n4)
{
    const long stride = (long)gridDim.x * 256;
    for (long i = (long)blockIdx.x * 256 + threadIdx.x; i < n4; i += stride) {
        f32x4 v = *(const f32x4*)(src + i * 4);
        ushort4 h, l;
        h.x = f2bf(v[0]); h.y = f2bf(v[1]); h.z = f2bf(v[2]); h.w = f2bf(v[3]);
        l.x = f2bf(v[0] - bf2f(h.x)); l.y = f2bf(v[1] - bf2f(h.y));
        l.z = f2bf(v[2] - bf2f(h.z)); l.w = f2bf(v[3] - bf2f(h.w));
        *(ushort4*)(hi + i * 4) = h;
        *(ushort4*)(lo + i * 4) = l;
    }
}

// ===========================================================================
// bf16-input MFMA GEMM: C = scale * A (.) B. Tile 128x128, BK=32, 4 waves.
// A: bf16 [M][lda] k-contiguous (copy-staged, stride 40, no XOR: frag reads are
//    2-way = free, staging b128 writes 16B-aligned).
// BT=true : B bf16 [N][ldb] k-contiguous, same copy staging.
// BT=false: B bf16 [K][ldb] n-contiguous; repack-staged into [n][k-pairs] on a
//    stride-36 plane with granule-4 XOR keyed on (n>>3)&7 (write & read ≤2-way).
// SPLIT: hi/lo planes, 3-MFMA emulation.
// ===========================================================================
#define ASTR 40
#define BSTR36 36
template<bool BT, bool SPLIT>
__global__ __launch_bounds__(256, 3) void gemm_bf16(
    const u16* __restrict__ Ah, const u16* __restrict__ Al,
    const u16* __restrict__ Bh, const u16* __restrict__ Bl,
    float* __restrict__ C,
    int Kd, int lda, int ldb, int ldc,
    long sA, long sB, long sC, float scale)
{
    constexpr int PL = SPLIT ? 2 : 1;
    __shared__ u16 As[PL][128 * ASTR];
    __shared__ u16 Bs[PL][BT ? 128 * ASTR : 128 * BSTR36];

    const int tid  = threadIdx.x;
    const int lane = tid & 63;
    const int wave = tid >> 6;
    const int wm = (wave >> 1) * 64, wn = (wave & 1) * 64;
    const int lr = lane & 15, kg = (lane >> 4) * 4;

    const int m0 = blockIdx.y * 128, n0 = blockIdx.x * 128;
    const u16* Ag[PL];
    const u16* Bg[PL];
    Ag[0] = Ah + (long)blockIdx.z * sA + (long)m0 * lda;
    Bg[0] = Bh + (long)blockIdx.z * sB + (BT ? (long)n0 * ldb : (long)n0);
    if constexpr (SPLIT) {
        Ag[1] = Al + (long)blockIdx.z * sA + (long)m0 * lda;
        Bg[1] = Bl + (long)blockIdx.z * sB + (BT ? (long)n0 * ldb : (long)n0);
    }

    f32x4 acc[4][4] = {};

    for (int k0 = 0; k0 < Kd; k0 += 32) {
        __syncthreads();

        // ---- A planes: straight bf16 copy, 2 x 16B per thread per plane ----
#pragma unroll
        for (int p = 0; p < PL; p++)
#pragma unroll
            for (int it = 0; it < 2; it++) {
                const int idx = tid + it * 256;
                const int row = idx >> 2, kc = (idx & 3) * 8;
                *(u16x8*)&As[p][row * ASTR + kc] =
                    *(const u16x8*)(Ag[p] + (long)row * lda + k0 + kc);
            }

        // ---- B planes ----
        if constexpr (BT) {
#pragma unroll
            for (int p = 0; p < PL; p++)
#pragma unroll
                for (int it = 0; it < 2; it++) {
                    const int idx = tid + it * 256;
                    const int row = idx >> 2, kc = (idx & 3) * 8;
                    *(u16x8*)&Bs[p][row * ASTR + kc] =
                        *(const u16x8*)(Bg[p] + (long)row * ldb + k0 + kc);
                }
        } else {
            // [32k x 128n] -> Bs[n][k] k-pairs. Each thread: 2 k-rows x 8 n.
            const int kk = (tid >> 4) * 2;
            const int nc = (tid & 15) * 8;
#pragma unroll
            for (int p = 0; p < PL; p++) {
                const u16* bsrc = Bg[p] + (long)(k0 + kk) * ldb + nc;
                uint4 r0 = *(const uint4*)bsrc;
                uint4 r1 = *(const uint4*)(bsrc + ldb);
                const unsigned* w0 = (const unsigned*)&r0;
                const unsigned* w1 = (const unsigned*)&r1;
#pragma unroll
                for (int j = 0; j < 8; j++) {
                    const unsigned a = w0[j >> 1], b = w1[j >> 1];
                    const unsigned w = (j & 1)
                        ? ((a >> 16) | (b & 0xffff0000u))
                        : ((a & 0x0000ffffu) | (b << 16));
                    const int n = nc + j;
                    const int kx = kk ^ (((n >> 3) & 7) << 2);
                    *(unsigned*)&Bs[p][n * BSTR36 + kx] = w;
                }
            }
        }
        __syncthreads();

        // ---- fragment loads ----
        bf16x8 af[PL][4], bf[PL][4];
#pragma unroll
        for (int i = 0; i < 4; i++) {
            const int r = wm + i * 16 + lr;
#pragma unroll
            for (int p = 0; p < PL; p++)
                af[p][i] = ld2(&As[p][0], r * ASTR + kg, r * ASTR + kg + 16);
        }
#pragma unroll
        for (int j = 0; j < 4; j++) {
            const int r = wn + j * 16 + lr;
#pragma unroll
            for (int p = 0; p < PL; p++) {
                if constexpr (BT) {
                    bf[p][j] = ld2(&Bs[p][0], r * ASTR + kg, r * ASTR + kg + 16);
                } else {
                    const int key = ((r >> 3) & 7) << 2;
                    bf[p][j] = ld2(&Bs[p][0],
                                   r * BSTR36 + (kg ^ key),
                                   r * BSTR36 + ((kg + 16) ^ key));
                }
            }
        }

        // ---- MFMA ----
#pragma unroll
        for (int i = 0; i < 4; i++)
#pragma unroll
            for (int j = 0; j < 4; j++) {
                acc[i][j] = __builtin_amdgcn_mfma_f32_16x16x32_bf16(
                    af[0][i], bf[0][j], acc[i][j], 0, 0, 0);
                if constexpr (SPLIT) {
                    acc[i][j] = __builtin_amdgcn_mfma_f32_16x16x32_bf16(
                        af[0][i], bf[1][j], acc[i][j], 0, 0, 0);
                    acc[i][j] = __builtin_amdgcn_mfma_f32_16x16x32_bf16(
                        af[1][i], bf[0][j], acc[i][j], 0, 0, 0);
                }
            }
    }

    // ---- epilogue: C/D layout col=lane&15, row=(lane>>4)*4+reg ----
    float* Cg = C + (long)blockIdx.z * sC + (long)(m0 + wm) * ldc + n0 + wn;
    const int rbase = (lane >> 4) * 4;
#pragma unroll
    for (int i = 0; i < 4; i++)
#pragma unroll
        for (int r = 0; r < 4; r++) {
            float* cp = Cg + (long)(i * 16 + rbase + r) * ldc + lr;
#pragma unroll
            for (int j = 0; j < 4; j++)
                cp[j * 16] = acc[i][j][r] * scale;
        }
}

// ===========================================================================
// Masked softmax over rows of 2048, in place on f32 scores; optionally also
// writes a bf16 copy (for the phase-4 A operand). One block per row.
// ===========================================================================
__global__ __launch_bounds__(256) void softmax_rows(
    float* __restrict__ att, const int* __restrict__ mask, u16* __restrict__ abf)
{
    const int  row  = blockIdx.x;                    // b*512 + k
    const int  tid  = threadIdx.x;
    const long base = (long)row * 2048 + tid * 8;

    f32x4 s0 = *(const f32x4*)(att + base);
    f32x4 s1 = *(const f32x4*)(att + base + 4);
    int4  mv0 = *(const int4*)(mask + base);
    int4  mv1 = *(const int4*)(mask + base + 4);
    const int mk[8] = {mv0.x, mv0.y, mv0.z, mv0.w, mv1.x, mv1.y, mv1.z, mv1.w};

    float x[8] = {s0[0], s0[1], s0[2], s0[3], s1[0], s1[1], s1[2], s1[3]};
#pragma unroll
    for (int j = 0; j < 8; j++) x[j] = mk[j] ? x[j] : -INFINITY;

    float mx = x[0];
#pragma unroll
    for (int j = 1; j < 8; j++) mx = fmaxf(mx, x[j]);
#pragma unroll
    for (int off = 32; off > 0; off >>= 1) mx = fmaxf(mx, __shfl_down(mx, off));

    __shared__ float red[8];
    const int wave = tid >> 6, lane = tid & 63;
    if (lane == 0) red[wave] = mx;
    __syncthreads();
    mx = fmaxf(fmaxf(red[0], red[1]), fmaxf(red[2], red[3]));

    if (mx == -INFINITY) {                           // all-masked row: zeros, not NaN
        f32x4 z = {0.f, 0.f, 0.f, 0.f};
        *(f32x4*)(att + base) = z;
        *(f32x4*)(att + base + 4) = z;
        if (abf) {
            u16x8 zb = {0, 0, 0, 0, 0, 0, 0, 0};
            *(u16x8*)(abf + base) = zb;
        }
        return;
    }

    float e[8], s = 0.f;
#pragma unroll
    for (int j = 0; j < 8; j++) { e[j] = __expf(x[j] - mx); s += e[j]; }
#pragma unroll
    for (int off = 32; off > 0; off >>= 1) s += __shfl_down(s, off);
    if (lane == 0) red[4 + wave] = s;
    __syncthreads();
    s = red[4] + red[5] + red[6] + red[7];

    const float inv = 1.f / s;
    float o[8];
#pragma unroll
    for (int j = 0; j < 8; j++) o[j] = e[j] * inv;
    f32x4 o0 = {o[0], o[1], o[2], o[3]}, o1 = {o[4], o[5], o[6], o[7]};
    *(f32x4*)(att + base) = o0;
    *(f32x4*)(att + base + 4) = o1;
    if (abf) {
        u16x8 pb;
#pragma unroll
        for (int j = 0; j < 8; j++) pb[j] = f2bf(o[j]);
        *(u16x8*)(abf + base) = pb;
    }
}

// ===========================================================================
extern "C" void kernel_launch(void* const* d_in, const int* in_sizes, int n_in,
                              void* d_out, int out_size, void* d_ws, size_t ws_size,
                              hipStream_t stream)
{
    const float* query = nullptr;   // 512*1024      = 524288
    const float* key   = nullptr;   // 16*2048*1024  = 33554432
    const float* W     = nullptr;   // 1024*1024     = 1048576
    const int*   mask  = nullptr;   // 16*512*2048   = 16777216
    for (int i = 0; i < n_in; i++) {
        switch (in_sizes[i]) {
            case 524288:   query = (const float*)d_in[i]; break;
            case 33554432: key   = (const float*)d_in[i]; break;
            case 1048576:  W     = (const float*)d_in[i]; break;
            case 16777216: mask  = (const int*)d_in[i];   break;
        }
    }

    float* out = (float*)d_out;                     // [16,512,1024] f32
    float* att = out + (long)16 * 512 * 1024;       // [16,512,2048] f32

    const long KEY_E = 16L * 2048 * 1024;           // 33,554,432
    const long ATT_E = 16L * 512 * 2048;            // 16,777,216
    const long QW_E  = 512L * 1024;                 //    524,288
    // ws layout: key_hi | key_lo | att_bf16 | qW_f32 | qW_hi | qW_lo
    const size_t WS_NEED = (size_t)(2 * KEY_E + ATT_E + 2 * QW_E) * 2 + QW_E * 4;

    if (ws_size >= WS_NEED && d_ws != nullptr) {
        u16*   key_hi = (u16*)d_ws;
        u16*   key_lo = key_hi + KEY_E;
        u16*   att_b  = key_lo + KEY_E;
        float* qW     = (float*)(att_b + ATT_E);
        u16*   qW_hi  = (u16*)(qW + QW_E);
        u16*   qW_lo  = qW_hi + QW_E;

        // 0) key f32 -> hi/lo bf16 planes (memory-bound, ~268 MB traffic)
        split_f32<<<dim3(4096), 256, 0, stream>>>(key, key_hi, key_lo, KEY_E / 4);

        // 1) qW = (query @ W) / 32   [512 x 1024], K=1024, fused-conv GEMM
        gemm_f32conv<false, true><<<dim3(8, 4, 1), 256, 0, stream>>>(
            query, W, qW, 1024, 1024, 1024, 1024, 0L, 0L, 0L, 1.f / 32.f);

        // 2) qW -> hi/lo planes (tiny)
        split_f32<<<dim3(512), 256, 0, stream>>>(qW, qW_hi, qW_lo, QW_E / 4);

        // 3) S[b] = qW @ key[b]^T    [512 x 2048], K=1024, split bf16-copy GEMM
        gemm_bf16<true, true><<<dim3(16, 4, 16), 256, 0, stream>>>(
            qW_hi, qW_lo, key_hi, key_lo, att,
            1024, 1024, 1024, 2048,
            0L, (long)2048 * 1024, (long)512 * 2048, 1.f);

        // 4) masked softmax, dual-write f32 + bf16
        softmax_rows<<<dim3(16 * 512), 256, 0, stream>>>(att, mask, att_b);

        // 5) out[b] = att[b] @ key[b]  [512 x 1024], K=2048, plain bf16 GEMM
        gemm_bf16<false, false><<<dim3(8, 4, 16), 256, 0, stream>>>(
            att_b, nullptr, key_hi, nullptr, out,
            2048, 2048, 1024, 1024,
            (long)512 * 2048, (long)2048 * 1024, (long)512 * 1024, 1.f);
    } else {
        // -------- fallback: round-1 path, no workspace --------
        float* qW = out;    // f32 scratch in out region (dead before phase 4)
        gemm_f32conv<false, true><<<dim3(8, 4, 1), 256, 0, stream>>>(
            query, W, qW, 1024, 1024, 1024, 1024, 0L, 0L, 0L, 1.f / 32.f);
        gemm_f32conv<true, true><<<dim3(16, 4, 16), 256, 0, stream>>>(
            qW, key, att, 1024, 1024, 1024, 2048,
            0L, (long)2048 * 1024, (long)512 * 2048, 1.f);
        softmax_rows<<<dim3(16 * 512), 256, 0, stream>>>(att, mask, nullptr);
        gemm_f32conv<false, false><<<dim3(8, 4, 16), 256, 0, stream>>>(
            att, key, out, 2048, 2048, 1024, 1024,
            (long)512 * 2048, (long)2048 * 1024, (long)512 * 1024, 1.f);
    }
}

// Round 4
// 529.918 us; speedup vs baseline: 2.6519x; 1.2280x over previous
//
#include <hip/hip_runtime.h>

// SimpleConcatAttention on MI355X — round 4: fix the low-occupancy phase 1.
// Round-3 post-mortem: phases 2/4 (bf16-copy-staged MFMA) left the top-5; the
// new #1 was phase 1 (gemm_f32conv, 155 µs, Occupancy 1.5%) — a 32-block grid
// on 256 CUs with fused conversion and no TLP to hide staging latency.
// Round 4: pre-split query/W to bf16 planes (scratch inside the att_b region,
// dead until softmax) and run phase 1 as a 64x64-tile, 128-block bf16 GEMM
// whose epilogue emits qW hi/lo planes directly (no f32 qW, no qW split pass).
//   0) split key   f32 -> key_hi/key_lo   (memory-bound, ~268 MB)
//   0b) split query, W                    (~18 MB, scratch in att_b region)
//   1) qW hi/lo = (q@W)/32                gemm_qw 64x64, 128 blocks
//   2) S = qW@key^T  split bf16 MFMA      (3-term: hh + hl + lh)
//   3) masked softmax f32, dual-write f32 + bf16
//   4) out = att@key plain bf16 MFMA
// Fallback (ws too small): round-1 fused-conversion path.

typedef float f32x4 __attribute__((ext_vector_type(4)));
typedef short bf16x8 __attribute__((ext_vector_type(8)));
typedef short s16x4 __attribute__((ext_vector_type(4)));
typedef unsigned short u16;
typedef unsigned short u16x8 __attribute__((ext_vector_type(8)));

// f32 -> bf16 (RNE) bit-twiddle (compiler-visible; proven), exact expand.
__device__ __forceinline__ u16 f2bf(float f) {
    unsigned int u = __float_as_uint(f);
    return (u16)((u + 0x7fffu + ((u >> 16) & 1u)) >> 16);
}
__device__ __forceinline__ float bf2f(u16 h) {
    return __uint_as_float(((unsigned int)h) << 16);
}

// Load 8 bf16 (two 8B halves) from LDS at two precomputed u16 offsets.
__device__ __forceinline__ bf16x8 ld2(const u16* p, int off1, int off2) {
    s16x4 a = *(const s16x4*)(p + off1);
    s16x4 b = *(const s16x4*)(p + off2);
    bf16x8 r = {a[0], a[1], a[2], a[3], b[0], b[1], b[2], b[3]};
    return r;
}

// ===========================================================================
// Round-1 fused-conversion GEMM — fallback path only.
// ===========================================================================
#define CSTR 36
__device__ __forceinline__ int swzc(int row, int k) {
    return row * CSTR + (k ^ (((row >> 2) & 7) << 2));
}
__device__ __forceinline__ bf16x8 ld_fragc(const u16* plane, int row, int kg) {
    return ld2(plane, swzc(row, kg), swzc(row, kg + 16));
}

template<bool BT, bool SPLIT>
__global__ __launch_bounds__(256, 2) void gemm_f32conv(
    const float* __restrict__ A, const float* __restrict__ B,
    float* __restrict__ C,
    int Kd, int lda, int ldb, int ldc,
    long sA, long sB, long sC, float scale)
{
    constexpr int PLANES = SPLIT ? 2 : 1;
    __shared__ u16 As[PLANES][128 * CSTR];
    __shared__ u16 Bs[PLANES][128 * CSTR];

    const int tid  = threadIdx.x;
    const int lane = tid & 63;
    const int wave = tid >> 6;
    const int wm = (wave >> 1) * 64, wn = (wave & 1) * 64;
    const int lr = lane & 15, kg = (lane >> 4) * 4;

    const int m0 = blockIdx.y * 128, n0 = blockIdx.x * 128;
    const float* Ag = A + (long)blockIdx.z * sA + (long)m0 * lda;
    const float* Bg = B + (long)blockIdx.z * sB + (BT ? (long)n0 * ldb : (long)n0);

    f32x4 acc[4][4] = {};

    for (int k0 = 0; k0 < Kd; k0 += 32) {
        __syncthreads();
#pragma unroll
        for (int it = 0; it < 4; it++) {
            const int idx = tid + it * 256;
            const int row = idx >> 3, kc = (idx & 7) * 4;
            f32x4 v = *(const f32x4*)(Ag + (long)row * lda + k0 + kc);
            ushort4 h;
            h.x = f2bf(v[0]); h.y = f2bf(v[1]); h.z = f2bf(v[2]); h.w = f2bf(v[3]);
            *(ushort4*)&As[0][swzc(row, kc)] = h;
            if constexpr (SPLIT) {
                ushort4 l;
                l.x = f2bf(v[0] - bf2f(h.x)); l.y = f2bf(v[1] - bf2f(h.y));
                l.z = f2bf(v[2] - bf2f(h.z)); l.w = f2bf(v[3] - bf2f(h.w));
                *(ushort4*)&As[1][swzc(row, kc)] = l;
            }
        }
        if constexpr (BT) {
#pragma unroll
            for (int it = 0; it < 4; it++) {
                const int idx = tid + it * 256;
                const int row = idx >> 3, kc = (idx & 7) * 4;
                f32x4 v = *(const f32x4*)(Bg + (long)row * ldb + k0 + kc);
                ushort4 h;
                h.x = f2bf(v[0]); h.y = f2bf(v[1]); h.z = f2bf(v[2]); h.w = f2bf(v[3]);
                *(ushort4*)&Bs[0][swzc(row, kc)] = h;
                if constexpr (SPLIT) {
                    ushort4 l;
                    l.x = f2bf(v[0] - bf2f(h.x)); l.y = f2bf(v[1] - bf2f(h.y));
                    l.z = f2bf(v[2] - bf2f(h.z)); l.w = f2bf(v[3] - bf2f(h.w));
                    *(ushort4*)&Bs[1][swzc(row, kc)] = l;
                }
            }
        } else {
#pragma unroll
            for (int it = 0; it < 2; it++) {
                const int idx = tid + it * 256;
                const int kk = (idx >> 5) * 2;
                const int nc = (idx & 31) * 4;
                f32x4 v0 = *(const f32x4*)(Bg + (long)(k0 + kk) * ldb + nc);
                f32x4 v1 = *(const f32x4*)(Bg + (long)(k0 + kk + 1) * ldb + nc);
#pragma unroll
                for (int e = 0; e < 4; e++) {
                    const u16 h0 = f2bf(v0[e]), h1 = f2bf(v1[e]);
                    *(unsigned*)&Bs[0][swzc(nc + e, kk)] =
                        (unsigned)h0 | ((unsigned)h1 << 16);
                    if constexpr (SPLIT) {
                        const u16 l0 = f2bf(v0[e] - bf2f(h0));
                        const u16 l1 = f2bf(v1[e] - bf2f(h1));
                        *(unsigned*)&Bs[1][swzc(nc + e, kk)] =
                            (unsigned)l0 | ((unsigned)l1 << 16);
                    }
                }
            }
        }
        __syncthreads();

        bf16x8 ah[4], bh[4], al[4], bl[4];
#pragma unroll
        for (int i = 0; i < 4; i++) {
            ah[i] = ld_fragc(&As[0][0], wm + i * 16 + lr, kg);
            if constexpr (SPLIT) al[i] = ld_fragc(&As[1][0], wm + i * 16 + lr, kg);
        }
#pragma unroll
        for (int j = 0; j < 4; j++) {
            bh[j] = ld_fragc(&Bs[0][0], wn + j * 16 + lr, kg);
            if constexpr (SPLIT) bl[j] = ld_fragc(&Bs[1][0], wn + j * 16 + lr, kg);
        }
#pragma unroll
        for (int i = 0; i < 4; i++)
#pragma unroll
            for (int j = 0; j < 4; j++) {
                acc[i][j] = __builtin_amdgcn_mfma_f32_16x16x32_bf16(
                    ah[i], bh[j], acc[i][j], 0, 0, 0);
                if constexpr (SPLIT) {
                    acc[i][j] = __builtin_amdgcn_mfma_f32_16x16x32_bf16(
                        ah[i], bl[j], acc[i][j], 0, 0, 0);
                    acc[i][j] = __builtin_amdgcn_mfma_f32_16x16x32_bf16(
                        al[i], bh[j], acc[i][j], 0, 0, 0);
                }
            }
    }

    float* Cg = C + (long)blockIdx.z * sC + (long)(m0 + wm) * ldc + n0 + wn;
    const int rbase = (lane >> 4) * 4;
#pragma unroll
    for (int i = 0; i < 4; i++)
#pragma unroll
        for (int r = 0; r < 4; r++) {
            float* cp = Cg + (long)(i * 16 + rbase + r) * ldc + lr;
#pragma unroll
            for (int j = 0; j < 4; j++)
                cp[j * 16] = acc[i][j][r] * scale;
        }
}

// ===========================================================================
// Elementwise split: src f32 -> hi/lo bf16 planes. n4 = element count / 4.
// ===========================================================================
__global__ __launch_bounds__(256) void split_f32(
    const float* __restrict__ src, u16* __restrict__ hi, u16* __restrict__ lo,
    long n4)
{
    const long stride = (long)gridDim.x * 256;
    for (long i = (long)blockIdx.x * 256 + threadIdx.x; i < n4; i += stride) {
        f32x4 v = *(const f32x4*)(src + i * 4);
        ushort4 h, l;
        h.x = f2bf(v[0]); h.y = f2bf(v[1]); h.z = f2bf(v[2]); h.w = f2bf(v[3]);
        l.x = f2bf(v[0] - bf2f(h.x)); l.y = f2bf(v[1] - bf2f(h.y));
        l.z = f2bf(v[2] - bf2f(h.z)); l.w = f2bf(v[3] - bf2f(h.w));
        *(ushort4*)(hi + i * 4) = h;
        *(ushort4*)(lo + i * 4) = l;
    }
}

// ===========================================================================
// bf16-input MFMA GEMM: C = scale * A (.) B. Tile 128x128, BK=32, 4 waves.
// (unchanged from round 3 — phases 2 and 4)
// ===========================================================================
#define ASTR 40
#define BSTR36 36
template<bool BT, bool SPLIT>
__global__ __launch_bounds__(256, 3) void gemm_bf16(
    const u16* __restrict__ Ah, const u16* __restrict__ Al,
    const u16* __restrict__ Bh, const u16* __restrict__ Bl,
    float* __restrict__ C,
    int Kd, int lda, int ldb, int ldc,
    long sA, long sB, long sC, float scale)
{
    constexpr int PL = SPLIT ? 2 : 1;
    __shared__ u16 As[PL][128 * ASTR];
    __shared__ u16 Bs[PL][BT ? 128 * ASTR : 128 * BSTR36];

    const int tid  = threadIdx.x;
    const int lane = tid & 63;
    const int wave = tid >> 6;
    const int wm = (wave >> 1) * 64, wn = (wave & 1) * 64;
    const int lr = lane & 15, kg = (lane >> 4) * 4;

    const int m0 = blockIdx.y * 128, n0 = blockIdx.x * 128;
    const u16* Ag[PL];
    const u16* Bg[PL];
    Ag[0] = Ah + (long)blockIdx.z * sA + (long)m0 * lda;
    Bg[0] = Bh + (long)blockIdx.z * sB + (BT ? (long)n0 * ldb : (long)n0);
    if constexpr (SPLIT) {
        Ag[1] = Al + (long)blockIdx.z * sA + (long)m0 * lda;
        Bg[1] = Bl + (long)blockIdx.z * sB + (BT ? (long)n0 * ldb : (long)n0);
    }

    f32x4 acc[4][4] = {};

    for (int k0 = 0; k0 < Kd; k0 += 32) {
        __syncthreads();

        // ---- A planes: straight bf16 copy, 2 x 16B per thread per plane ----
#pragma unroll
        for (int p = 0; p < PL; p++)
#pragma unroll
            for (int it = 0; it < 2; it++) {
                const int idx = tid + it * 256;
                const int row = idx >> 2, kc = (idx & 3) * 8;
                *(u16x8*)&As[p][row * ASTR + kc] =
                    *(const u16x8*)(Ag[p] + (long)row * lda + k0 + kc);
            }

        // ---- B planes ----
        if constexpr (BT) {
#pragma unroll
            for (int p = 0; p < PL; p++)
#pragma unroll
                for (int it = 0; it < 2; it++) {
                    const int idx = tid + it * 256;
                    const int row = idx >> 2, kc = (idx & 3) * 8;
                    *(u16x8*)&Bs[p][row * ASTR + kc] =
                        *(const u16x8*)(Bg[p] + (long)row * ldb + k0 + kc);
                }
        } else {
            // [32k x 128n] -> Bs[n][k] k-pairs. Each thread: 2 k-rows x 8 n.
            const int kk = (tid >> 4) * 2;
            const int nc = (tid & 15) * 8;
#pragma unroll
            for (int p = 0; p < PL; p++) {
                const u16* bsrc = Bg[p] + (long)(k0 + kk) * ldb + nc;
                uint4 r0 = *(const uint4*)bsrc;
                uint4 r1 = *(const uint4*)(bsrc + ldb);
                const unsigned* w0 = (const unsigned*)&r0;
                const unsigned* w1 = (const unsigned*)&r1;
#pragma unroll
                for (int j = 0; j < 8; j++) {
                    const unsigned a = w0[j >> 1], b = w1[j >> 1];
                    const unsigned w = (j & 1)
                        ? ((a >> 16) | (b & 0xffff0000u))
                        : ((a & 0x0000ffffu) | (b << 16));
                    const int n = nc + j;
                    const int kx = kk ^ (((n >> 3) & 7) << 2);
                    *(unsigned*)&Bs[p][n * BSTR36 + kx] = w;
                }
            }
        }
        __syncthreads();

        // ---- fragment loads ----
        bf16x8 af[PL][4], bf[PL][4];
#pragma unroll
        for (int i = 0; i < 4; i++) {
            const int r = wm + i * 16 + lr;
#pragma unroll
            for (int p = 0; p < PL; p++)
                af[p][i] = ld2(&As[p][0], r * ASTR + kg, r * ASTR + kg + 16);
        }
#pragma unroll
        for (int j = 0; j < 4; j++) {
            const int r = wn + j * 16 + lr;
#pragma unroll
            for (int p = 0; p < PL; p++) {
                if constexpr (BT) {
                    bf[p][j] = ld2(&Bs[p][0], r * ASTR + kg, r * ASTR + kg + 16);
                } else {
                    const int key = ((r >> 3) & 7) << 2;
                    bf[p][j] = ld2(&Bs[p][0],
                                   r * BSTR36 + (kg ^ key),
                                   r * BSTR36 + ((kg + 16) ^ key));
                }
            }
        }

        // ---- MFMA ----
#pragma unroll
        for (int i = 0; i < 4; i++)
#pragma unroll
            for (int j = 0; j < 4; j++) {
                acc[i][j] = __builtin_amdgcn_mfma_f32_16x16x32_bf16(
                    af[0][i], bf[0][j], acc[i][j], 0, 0, 0);
                if constexpr (SPLIT) {
                    acc[i][j] = __builtin_amdgcn_mfma_f32_16x16x32_bf16(
                        af[0][i], bf[1][j], acc[i][j], 0, 0, 0);
                    acc[i][j] = __builtin_amdgcn_mfma_f32_16x16x32_bf16(
                        af[1][i], bf[0][j], acc[i][j], 0, 0, 0);
                }
            }
    }

    // ---- epilogue: C/D layout col=lane&15, row=(lane>>4)*4+reg ----
    float* Cg = C + (long)blockIdx.z * sC + (long)(m0 + wm) * ldc + n0 + wn;
    const int rbase = (lane >> 4) * 4;
#pragma unroll
    for (int i = 0; i < 4; i++)
#pragma unroll
        for (int r = 0; r < 4; r++) {
            float* cp = Cg + (long)(i * 16 + rbase + r) * ldc + lr;
#pragma unroll
            for (int j = 0; j < 4; j++)
                cp[j * 16] = acc[i][j][r] * scale;
        }
}

// ===========================================================================
// Phase-1 kernel: qW = (query @ W)/32, split bf16 inputs, hi/lo bf16 OUTPUT.
// Shapes fixed: M=512, N=1024, K=1024, all ld = 1024.
// Tile 64x64, BK=32, 4 waves (each 32x32 = 2x2 frags), grid (16,8) = 128 blocks
// — 4x the parallelism of the old 128^2-tile phase 1 (which ran 32 blocks at
// 1.5% occupancy, 155 µs) plus copy-only staging.
// ===========================================================================
__global__ __launch_bounds__(256, 2) void gemm_qw(
    const u16* __restrict__ qh, const u16* __restrict__ ql,
    const u16* __restrict__ Wh, const u16* __restrict__ Wl,
    u16* __restrict__ qWh, u16* __restrict__ qWl)
{
    __shared__ u16 As[2][64 * ASTR];
    __shared__ u16 Bs[2][64 * BSTR36];

    const int tid  = threadIdx.x;
    const int lane = tid & 63;
    const int wave = tid >> 6;
    const int wm = (wave >> 1) * 32, wn = (wave & 1) * 32;
    const int lr = lane & 15, kg = (lane >> 4) * 4;
    const int m0 = blockIdx.y * 64, n0 = blockIdx.x * 64;

    const u16* Ag[2] = { qh + (long)m0 * 1024, ql + (long)m0 * 1024 };
    const u16* Bg[2] = { Wh + n0, Wl + n0 };

    f32x4 acc[2][2] = {};

    for (int k0 = 0; k0 < 1024; k0 += 32) {
        __syncthreads();
        // A: 64 rows x 32 k per plane; 256 thr x 16B covers a full plane.
        {
            const int row = tid >> 2, kc = (tid & 3) * 8;
#pragma unroll
            for (int p = 0; p < 2; p++)
                *(u16x8*)&As[p][row * ASTR + kc] =
                    *(const u16x8*)(Ag[p] + (long)row * 1024 + k0 + kc);
        }
        // B: [32 k x 64 n] -> Bs[n][k] k-pairs; thread: 1 k-pair x 4 n.
        {
            const int kk = (tid >> 4) * 2, nc = (tid & 15) * 4;
#pragma unroll
            for (int p = 0; p < 2; p++) {
                const u16* bsrc = Bg[p] + (long)(k0 + kk) * 1024 + nc;
                uint2 r0 = *(const uint2*)bsrc;
                uint2 r1 = *(const uint2*)(bsrc + 1024);
                const unsigned* w0 = (const unsigned*)&r0;
                const unsigned* w1 = (const unsigned*)&r1;
#pragma unroll
                for (int j = 0; j < 4; j++) {
                    const unsigned a = w0[j >> 1], b = w1[j >> 1];
                    const unsigned w = (j & 1)
                        ? ((a >> 16) | (b & 0xffff0000u))
                        : ((a & 0x0000ffffu) | (b << 16));
                    const int n = nc + j;
                    *(unsigned*)&Bs[p][n * BSTR36 + (kk ^ (((n >> 3) & 7) << 2))] = w;
                }
            }
        }
        __syncthreads();

        bf16x8 af[2][2], bfr[2][2];
#pragma unroll
        for (int i = 0; i < 2; i++) {
            const int r = wm + i * 16 + lr;
#pragma unroll
            for (int p = 0; p < 2; p++)
                af[p][i] = ld2(&As[p][0], r * ASTR + kg, r * ASTR + kg + 16);
        }
#pragma unroll
        for (int j = 0; j < 2; j++) {
            const int r = wn + j * 16 + lr;
            const int key = ((r >> 3) & 7) << 2;
#pragma unroll
            for (int p = 0; p < 2; p++)
                bfr[p][j] = ld2(&Bs[p][0], r * BSTR36 + (kg ^ key),
                                r * BSTR36 + ((kg + 16) ^ key));
        }
#pragma unroll
        for (int i = 0; i < 2; i++)
#pragma unroll
            for (int j = 0; j < 2; j++) {
                acc[i][j] = __builtin_amdgcn_mfma_f32_16x16x32_bf16(
                    af[0][i], bfr[0][j], acc[i][j], 0, 0, 0);
                acc[i][j] = __builtin_amdgcn_mfma_f32_16x16x32_bf16(
                    af[0][i], bfr[1][j], acc[i][j], 0, 0, 0);
                acc[i][j] = __builtin_amdgcn_mfma_f32_16x16x32_bf16(
                    af[1][i], bfr[0][j], acc[i][j], 0, 0, 0);
            }
    }

    // Epilogue: scale by 1/32 and split-write hi/lo bf16 planes directly.
    const int rbase = (lane >> 4) * 4;
#pragma unroll
    for (int i = 0; i < 2; i++)
#pragma unroll
        for (int r = 0; r < 4; r++) {
            const long ro = (long)(m0 + wm + i * 16 + rbase + r) * 1024 + n0 + wn + lr;
#pragma unroll
            for (int j = 0; j < 2; j++) {
                const float v = acc[i][j][r] * (1.f / 32.f);
                const u16 h = f2bf(v);
                qWh[ro + j * 16] = h;
                qWl[ro + j * 16] = f2bf(v - bf2f(h));
            }
        }
}

// ===========================================================================
// Masked softmax over rows of 2048, in place on f32 scores; optionally also
// writes a bf16 copy (for the phase-4 A operand). One block per row.
// ===========================================================================
__global__ __launch_bounds__(256) void softmax_rows(
    float* __restrict__ att, const int* __restrict__ mask, u16* __restrict__ abf)
{
    const int  row  = blockIdx.x;                    // b*512 + k
    const int  tid  = threadIdx.x;
    const long base = (long)row * 2048 + tid * 8;

    f32x4 s0 = *(const f32x4*)(att + base);
    f32x4 s1 = *(const f32x4*)(att + base + 4);
    int4  mv0 = *(const int4*)(mask + base);
    int4  mv1 = *(const int4*)(mask + base + 4);
    const int mk[8] = {mv0.x, mv0.y, mv0.z, mv0.w, mv1.x, mv1.y, mv1.z, mv1.w};

    float x[8] = {s0[0], s0[1], s0[2], s0[3], s1[0], s1[1], s1[2], s1[3]};
#pragma unroll
    for (int j = 0; j < 8; j++) x[j] = mk[j] ? x[j] : -INFINITY;

    float mx = x[0];
#pragma unroll
    for (int j = 1; j < 8; j++) mx = fmaxf(mx, x[j]);
#pragma unroll
    for (int off = 32; off > 0; off >>= 1) mx = fmaxf(mx, __shfl_down(mx, off));

    __shared__ float red[8];
    const int wave = tid >> 6, lane = tid & 63;
    if (lane == 0) red[wave] = mx;
    __syncthreads();
    mx = fmaxf(fmaxf(red[0], red[1]), fmaxf(red[2], red[3]));

    if (mx == -INFINITY) {                           // all-masked row: zeros, not NaN
        f32x4 z = {0.f, 0.f, 0.f, 0.f};
        *(f32x4*)(att + base) = z;
        *(f32x4*)(att + base + 4) = z;
        if (abf) {
            u16x8 zb = {0, 0, 0, 0, 0, 0, 0, 0};
            *(u16x8*)(abf + base) = zb;
        }
        return;
    }

    float e[8], s = 0.f;
#pragma unroll
    for (int j = 0; j < 8; j++) { e[j] = __expf(x[j] - mx); s += e[j]; }
#pragma unroll
    for (int off = 32; off > 0; off >>= 1) s += __shfl_down(s, off);
    if (lane == 0) red[4 + wave] = s;
    __syncthreads();
    s = red[4] + red[5] + red[6] + red[7];

    const float inv = 1.f / s;
    float o[8];
#pragma unroll
    for (int j = 0; j < 8; j++) o[j] = e[j] * inv;
    f32x4 o0 = {o[0], o[1], o[2], o[3]}, o1 = {o[4], o[5], o[6], o[7]};
    *(f32x4*)(att + base) = o0;
    *(f32x4*)(att + base + 4) = o1;
    if (abf) {
        u16x8 pb;
#pragma unroll
        for (int j = 0; j < 8; j++) pb[j] = f2bf(o[j]);
        *(u16x8*)(abf + base) = pb;
    }
}

// ===========================================================================
extern "C" void kernel_launch(void* const* d_in, const int* in_sizes, int n_in,
                              void* d_out, int out_size, void* d_ws, size_t ws_size,
                              hipStream_t stream)
{
    const float* query = nullptr;   // 512*1024      = 524288
    const float* key   = nullptr;   // 16*2048*1024  = 33554432
    const float* W     = nullptr;   // 1024*1024     = 1048576
    const int*   mask  = nullptr;   // 16*512*2048   = 16777216
    for (int i = 0; i < n_in; i++) {
        switch (in_sizes[i]) {
            case 524288:   query = (const float*)d_in[i]; break;
            case 33554432: key   = (const float*)d_in[i]; break;
            case 1048576:  W     = (const float*)d_in[i]; break;
            case 16777216: mask  = (const int*)d_in[i];   break;
        }
    }

    float* out = (float*)d_out;                     // [16,512,1024] f32
    float* att = out + (long)16 * 512 * 1024;       // [16,512,2048] f32

    const long KEY_E = 16L * 2048 * 1024;           // 33,554,432
    const long ATT_E = 16L * 512 * 2048;            // 16,777,216
    const long QW_E  = 512L * 1024;                 //    524,288 (query & qW)
    const long W_E   = 1024L * 1024;                //  1,048,576
    // ws layout: key_hi | key_lo | att_b | qW_hi | qW_lo
    // q_hi/q_lo/W_hi/W_lo live INSIDE the att_b region (dead until softmax;
    // needs 2*QW_E + 2*W_E = 3,145,728 u16 <= ATT_E). Total <= round-3's need.
    const size_t WS_NEED = (size_t)(2 * KEY_E + ATT_E + 2 * QW_E) * 2;

    if (ws_size >= WS_NEED && d_ws != nullptr) {
        u16* key_hi = (u16*)d_ws;
        u16* key_lo = key_hi + KEY_E;
        u16* att_b  = key_lo + KEY_E;
        u16* qW_hi  = att_b + ATT_E;
        u16* qW_lo  = qW_hi + QW_E;
        // phase-1 scratch aliased into att_b (released at softmax time):
        u16* q_hi   = att_b;
        u16* q_lo   = q_hi + QW_E;
        u16* W_hi   = q_lo + QW_E;
        u16* W_lo   = W_hi + W_E;

        // 0) split key / query / W into hi+lo bf16 planes (memory-bound)
        split_f32<<<dim3(4096), 256, 0, stream>>>(key, key_hi, key_lo, KEY_E / 4);
        split_f32<<<dim3(512),  256, 0, stream>>>(query, q_hi, q_lo, QW_E / 4);
        split_f32<<<dim3(1024), 256, 0, stream>>>(W, W_hi, W_lo, W_E / 4);

        // 1) qW hi/lo = (query @ W) / 32   [512 x 1024], 128 blocks
        gemm_qw<<<dim3(16, 8, 1), 256, 0, stream>>>(
            q_hi, q_lo, W_hi, W_lo, qW_hi, qW_lo);

        // 2) S[b] = qW @ key[b]^T    [512 x 2048], K=1024, split bf16 GEMM
        gemm_bf16<true, true><<<dim3(16, 4, 16), 256, 0, stream>>>(
            qW_hi, qW_lo, key_hi, key_lo, att,
            1024, 1024, 1024, 2048,
            0L, (long)2048 * 1024, (long)512 * 2048, 1.f);

        // 3) masked softmax, dual-write f32 + bf16 (overwrites q/W scratch)
        softmax_rows<<<dim3(16 * 512), 256, 0, stream>>>(att, mask, att_b);

        // 4) out[b] = att[b] @ key[b]  [512 x 1024], K=2048, plain bf16 GEMM
        gemm_bf16<false, false><<<dim3(8, 4, 16), 256, 0, stream>>>(
            att_b, nullptr, key_hi, nullptr, out,
            2048, 2048, 1024, 1024,
            (long)512 * 2048, (long)2048 * 1024, (long)512 * 1024, 1.f);
    } else {
        // -------- fallback: round-1 path, no workspace --------
        float* qW = out;    // f32 scratch in out region (dead before phase 4)
        gemm_f32conv<false, true><<<dim3(8, 4, 1), 256, 0, stream>>>(
            query, W, qW, 1024, 1024, 1024, 1024, 0L, 0L, 0L, 1.f / 32.f);
        gemm_f32conv<true, true><<<dim3(16, 4, 16), 256, 0, stream>>>(
            qW, key, att, 1024, 1024, 1024, 2048,
            0L, (long)2048 * 1024, (long)512 * 2048, 1.f);
        softmax_rows<<<dim3(16 * 512), 256, 0, stream>>>(att, mask, nullptr);
        gemm_f32conv<false, false><<<dim3(8, 4, 16), 256, 0, stream>>>(
            att, key, out, 2048, 2048, 1024, 1024,
            (long)512 * 2048, (long)2048 * 1024, (long)512 * 1024, 1.f);
    }
}